// Round 1
// baseline (3739.544 us; speedup 1.0000x reference)
//
#include <hip/hip_runtime.h>
#include <math.h>

// Vision Mamba fp32 baseline.
// Sizes: B=16, L=196 tokens, D_MODEL=384, D_INNER=768, N_STATE=16, DT_RANK=24,
// DEPTH=8, ROWS = B*L = 3136.

#define L_TOK 196
#define ROWS  3136

__device__ __forceinline__ float sigmoidf_(float x) { return 1.f / (1.f + __expf(-x)); }

// ---------------- patchify: x[B,3,224,224] -> patches[3136,768] -------------
__global__ void patchify_kernel(const float* __restrict__ x, float* __restrict__ p) {
    int row = blockIdx.x;            // b*196 + l
    int t   = threadIdx.x;           // 0..255  -> (iy,ix)
    int b = row / L_TOK, l = row % L_TOK;
    int py = l / 14, px = l % 14;
    int iy = t >> 4, ix = t & 15;
    int Y = py * 16 + iy, X = px * 16 + ix;
#pragma unroll
    for (int c = 0; c < 3; ++c) {
        float v = x[((size_t)(b * 3 + c) * 224 + Y) * 224 + X];
        p[(size_t)row * 768 + c * 256 + t] = v;
    }
}

// ---------------- generic fp32 tiled GEMM: C[M,N] = A[M,K]@B[K,N] -----------
// EPI: 0 = none, 1 = +bias[n] + pos[(r%196)*N+n], 2 = softplus(+bias[n]),
//      3 = +res (residual add)
// M is implicit: grid.y*64 rows, M always divisible by 64 here.
template <int EPI>
__global__ __launch_bounds__(256) void gemm_kernel(
    const float* __restrict__ A, int lda,
    const float* __restrict__ B, int ldb,
    float* __restrict__ C, int ldc,
    int N, int K,
    const float* __restrict__ bias,
    const float* __restrict__ pos,
    const float* __restrict__ res) {
    __shared__ __align__(16) float As[16][68];   // [k][m], padded: write ~2-way, read b128
    __shared__ __align__(16) float Bs[16][64];   // [k][n]
    int t = threadIdx.x;
    int tx = t & 15, ty = t >> 4;
    int row0 = blockIdx.y * 64;
    int col0 = blockIdx.x * 64;
    float acc[4][4] = {};

    for (int k0 = 0; k0 < K; k0 += 16) {
        // A tile 64x16 -> As[k][m]
#pragma unroll
        for (int i = 0; i < 4; ++i) {
            int idx = t + i * 256;
            int m = idx >> 4, kk = idx & 15;
            float v = 0.f;
            if (k0 + kk < K) v = A[(size_t)(row0 + m) * lda + k0 + kk];
            As[kk][m] = v;
        }
        // B tile 16x64 -> Bs[k][n]
#pragma unroll
        for (int i = 0; i < 4; ++i) {
            int idx = t + i * 256;
            int kk = idx >> 6, n = idx & 63;
            float v = 0.f;
            if ((k0 + kk) < K && (col0 + n) < N) v = B[(size_t)(k0 + kk) * ldb + col0 + n];
            Bs[kk][n] = v;
        }
        __syncthreads();
#pragma unroll
        for (int kk = 0; kk < 16; ++kk) {
            float4 av = *(const float4*)&As[kk][ty * 4];
            float4 bv = *(const float4*)&Bs[kk][tx * 4];
            float a_[4] = {av.x, av.y, av.z, av.w};
            float b_[4] = {bv.x, bv.y, bv.z, bv.w};
#pragma unroll
            for (int i = 0; i < 4; ++i)
#pragma unroll
                for (int j = 0; j < 4; ++j)
                    acc[i][j] = fmaf(a_[i], b_[j], acc[i][j]);
        }
        __syncthreads();
    }

#pragma unroll
    for (int i = 0; i < 4; ++i) {
        int r = row0 + ty * 4 + i;
#pragma unroll
        for (int j = 0; j < 4; ++j) {
            int c = col0 + tx * 4 + j;
            if (c < N) {
                float v = acc[i][j];
                if (EPI == 1) v += bias[c] + pos[(size_t)(r % L_TOK) * N + c];
                if (EPI == 2) {
                    v += bias[c];
                    v = (v > 20.f) ? v : log1pf(__expf(v));
                }
                if (EPI == 3) v += res[(size_t)r * ldc + c];
                C[(size_t)r * ldc + c] = v;
            }
        }
    }
}

// ---------------- causal depthwise conv1d (d_conv=4) + SiLU -----------------
// reads x-half of xz [ROWS,1536], writes xconv [ROWS,768]
__global__ void conv_silu_kernel(const float* __restrict__ xz,
                                 const float* __restrict__ w,   // [768,4]
                                 const float* __restrict__ bb,  // [768]
                                 float* __restrict__ out) {
    int idx = blockIdx.x * 256 + threadIdx.x;  // ROWS*768
    int di = idx % 768;
    int row = idx / 768;
    int l = row % L_TOK;
    int rowbase = row - l;  // b*196
    float s = bb[di];
#pragma unroll
    for (int j = 0; j < 4; ++j) {
        int ll = l - 3 + j;
        if (ll >= 0) s = fmaf(w[di * 4 + j], xz[(size_t)(rowbase + ll) * 1536 + di], s);
    }
    out[(size_t)row * 768 + di] = s * sigmoidf_(s);
}

// ---------------- LayerNorm (one wave per row, 384 elems) -------------------
__global__ void ln_kernel(const float* __restrict__ in, const float* __restrict__ w,
                          const float* __restrict__ b, float* __restrict__ out) {
    int row = blockIdx.x;
    int t = threadIdx.x;  // 0..63
    float v[6];
    float s1 = 0.f, s2 = 0.f;
#pragma unroll
    for (int j = 0; j < 6; ++j) {
        float xv = in[(size_t)row * 384 + t + j * 64];
        v[j] = xv;
        s1 += xv;
        s2 += xv * xv;
    }
#pragma unroll
    for (int off = 32; off >= 1; off >>= 1) {
        s1 += __shfl_xor(s1, off);
        s2 += __shfl_xor(s2, off);
    }
    float mu = s1 * (1.f / 384.f);
    float var = s2 * (1.f / 384.f) - mu * mu;
    float rs = rsqrtf(var + 1e-5f);
#pragma unroll
    for (int j = 0; j < 6; ++j) {
        int e = t + j * 64;
        out[(size_t)row * 384 + e] = (v[j] - mu) * rs * w[e] + b[e];
    }
}

// ---------------- selective scan + gating -----------------------------------
// 16 lanes per (b,di) channel, one lane per state n. 4 channels per wave.
__global__ __launch_bounds__(256) void scan_kernel(
    const float* __restrict__ u,     // xconv [ROWS,768]
    const float* __restrict__ dt,    // [ROWS,768]
    const float* __restrict__ proj,  // [ROWS,56]: B at 24..39, C at 40..55
    const float* __restrict__ xz,    // z at [row,768+di]
    const float* __restrict__ A_log, // [768,16]
    const float* __restrict__ Dskip, // [768]
    float* __restrict__ yg)          // [ROWS,768]
{
    int tid = blockIdx.x * 256 + threadIdx.x;
    int g = tid >> 4;   // b*768 + di
    int n = tid & 15;
    int b = g / 768, di = g % 768;
    float a = -expf(A_log[di * 16 + n]);
    float dsk = Dskip[di];
    float h = 0.f;
    int rowbase = b * L_TOK;
    for (int l = 0; l < L_TOK; ++l) {
        int row = rowbase + l;
        float dtv = dt[(size_t)row * 768 + di];
        float uv  = u[(size_t)row * 768 + di];
        float Bn  = proj[(size_t)row * 56 + 24 + n];
        float Cn  = proj[(size_t)row * 56 + 40 + n];
        h = __expf(dtv * a) * h + dtv * Bn * uv;
        float p = h * Cn;
        p += __shfl_xor(p, 1);
        p += __shfl_xor(p, 2);
        p += __shfl_xor(p, 4);
        p += __shfl_xor(p, 8);
        if (n == 0) {
            float y = p + uv * dsk;
            float z = xz[(size_t)row * 1536 + 768 + di];
            yg[(size_t)row * 768 + di] = y * z * sigmoidf_(z);
        }
    }
}

// ---------------- final: mean-pool + heads ----------------------------------
__global__ void pool_heads_kernel(const float* __restrict__ ln_out,  // [ROWS,384]
                                  const float* __restrict__ wdev, const float* __restrict__ bdev,
                                  const float* __restrict__ wdist, const float* __restrict__ bdist,
                                  float* __restrict__ out) {  // [16,11]
    __shared__ float pooled[384];
    int b = blockIdx.x;
    int m = threadIdx.x;  // 0..383
    float s = 0.f;
    for (int l = 0; l < L_TOK; ++l) s += ln_out[(size_t)(b * L_TOK + l) * 384 + m];
    pooled[m] = s * (1.f / (float)L_TOK);
    __syncthreads();
    if (m < 11) {
        float acc;
        const float* w;
        int nc, c;
        if (m < 7) { acc = bdev[m]; w = wdev; nc = 7; c = m; }
        else       { acc = bdist[m - 7]; w = wdist; nc = 4; c = m - 7; }
        for (int k = 0; k < 384; ++k) acc += pooled[k] * w[k * nc + c];
        out[b * 11 + m] = acc;
    }
}

extern "C" void kernel_launch(void* const* d_in, const int* in_sizes, int n_in,
                              void* d_out, int out_size, void* d_ws, size_t ws_size,
                              hipStream_t stream) {
    const float* x       = (const float*)d_in[0];
    const float* patch_w = (const float*)d_in[1];
    const float* patch_b = (const float*)d_in[2];
    const float* pos_emb = (const float*)d_in[3];
    const float* ln_w    = (const float*)d_in[4];
    const float* ln_b    = (const float*)d_in[5];
    const float* in_w    = (const float*)d_in[6];
    const float* conv_w  = (const float*)d_in[7];
    const float* conv_b  = (const float*)d_in[8];
    const float* xproj_w = (const float*)d_in[9];
    const float* dt_w    = (const float*)d_in[10];
    const float* dt_b    = (const float*)d_in[11];
    const float* A_log   = (const float*)d_in[12];
    const float* D_skip  = (const float*)d_in[13];
    const float* out_w   = (const float*)d_in[14];
    const float* fnorm_w = (const float*)d_in[15];
    const float* fnorm_b = (const float*)d_in[16];
    const float* hdev_w  = (const float*)d_in[17];
    const float* hdev_b  = (const float*)d_in[18];
    const float* hdist_w = (const float*)d_in[19];
    const float* hdist_b = (const float*)d_in[20];

    float* ws    = (float*)d_ws;
    float* h     = ws;                 // 3136*384  = 1204224
    float* u     = h + 1204224;        // 1204224
    float* xz    = u + 1204224;        // 3136*1536 = 4816896
    float* xconv = xz + 4816896;       // 3136*768  = 2408448
    float* proj  = xconv + 2408448;    // 3136*56   = 175616
    float* dtb   = proj + 175616;      // 2408448
    float* yg    = dtb + 2408448;      // 2408448   (total ~58.5 MB)
    float* patches = xz;               // alias: xz unused until first in_proj

    patchify_kernel<<<ROWS, 256, 0, stream>>>(x, patches);
    // h = patches @ patch_w + patch_b + pos_emb
    gemm_kernel<1><<<dim3(6, 49), 256, 0, stream>>>(patches, 768, patch_w, 384, h, 384,
                                                    384, 768, patch_b, pos_emb, nullptr);
    for (int i = 0; i < 8; ++i) {
        ln_kernel<<<ROWS, 64, 0, stream>>>(h, ln_w + i * 384, ln_b + i * 384, u);
        // xz = u @ in_proj_w[i]   [3136,1536]
        gemm_kernel<0><<<dim3(24, 49), 256, 0, stream>>>(u, 384, in_w + (size_t)i * 384 * 1536, 1536,
                                                         xz, 1536, 1536, 384, nullptr, nullptr, nullptr);
        conv_silu_kernel<<<9408, 256, 0, stream>>>(xz, conv_w + i * 3072, conv_b + i * 768, xconv);
        // proj = xconv @ xproj_w[i]   [3136,56]
        gemm_kernel<0><<<dim3(1, 49), 256, 0, stream>>>(xconv, 768, xproj_w + (size_t)i * 768 * 56, 56,
                                                        proj, 56, 56, 768, nullptr, nullptr, nullptr);
        // dt = softplus(proj[:, :24] @ dt_w[i] + dt_b[i])   [3136,768]
        gemm_kernel<2><<<dim3(12, 49), 256, 0, stream>>>(proj, 56, dt_w + (size_t)i * 24 * 768, 768,
                                                         dtb, 768, 768, 24, dt_b + i * 768, nullptr, nullptr);
        scan_kernel<<<768, 256, 0, stream>>>(xconv, dtb, proj, xz,
                                             A_log + (size_t)i * 768 * 16, D_skip + i * 768, yg);
        // h += yg @ out_proj_w[i]
        gemm_kernel<3><<<dim3(6, 49), 256, 0, stream>>>(yg, 768, out_w + (size_t)i * 768 * 384, 384,
                                                        h, 384, 384, 768, nullptr, nullptr, h);
    }
    ln_kernel<<<ROWS, 64, 0, stream>>>(h, fnorm_w, fnorm_b, u);
    pool_heads_kernel<<<16, 384, 0, stream>>>(u, hdev_w, hdev_b, hdist_w, hdist_b, (float*)d_out);
}

// Round 2
// 1866.502 us; speedup vs baseline: 2.0035x; 2.0035x over previous
//
#include <hip/hip_runtime.h>
#include <math.h>

// Vision Mamba: bf16-MFMA GEMMs + fused dt+scan, fp32 residual stream.
// B=16, L=196, ROWS=3136, D_MODEL=384, D_INNER=768, N_STATE=16, DT_RANK=24, DEPTH=8.

#define L_TOK 196
#define ROWS  3136

typedef unsigned short u16;
typedef __attribute__((ext_vector_type(8))) short bf16x8;
typedef __attribute__((ext_vector_type(4))) float f32x4;

__device__ __forceinline__ float sigmoidf_(float x) { return 1.f / (1.f + __expf(-x)); }
__device__ __forceinline__ u16 f2b(float f) {
    union { float f; unsigned u; } v; v.f = f;
    unsigned r = v.u + 0x7FFF + ((v.u >> 16) & 1);
    return (u16)(r >> 16);
}
__device__ __forceinline__ float b2f(u16 s) {
    union { unsigned u; float f; } v; v.u = (unsigned)s << 16; return v.f;
}

// ---------------- patchify: x[B,3,224,224] -> patches[3136,768] bf16 --------
__global__ void patchify_kernel(const float* __restrict__ x, u16* __restrict__ p) {
    int row = blockIdx.x;            // b*196 + l
    int t   = threadIdx.x;           // 0..255
    int b = row / L_TOK, l = row % L_TOK;
    int py = l / 14, px = l % 14;
    int iy = t >> 4, ix = t & 15;
    int Y = py * 16 + iy, X = px * 16 + ix;
#pragma unroll
    for (int c = 0; c < 3; ++c) {
        float v = x[((size_t)(b * 3 + c) * 224 + Y) * 224 + X];
        p[(size_t)row * 768 + c * 256 + t] = f2b(v);
    }
}

// ---------------- transpose+convert: src fp32 [K][N] -> dst bf16 [Np][K] ----
__global__ __launch_bounds__(256) void transpose_cvt(
    const float* __restrict__ src, u16* __restrict__ dst,
    int K, int N, int Np, int src_stride, int dst_stride) {
    __shared__ float tile[32][33];
    int n0 = blockIdx.x * 32, k0 = blockIdx.y * 32;
    const float* s = src + (size_t)blockIdx.z * src_stride;
    u16* d = dst + (size_t)blockIdx.z * dst_stride;
    int tx = threadIdx.x & 31, ty = threadIdx.x >> 5;   // 32 x 8
#pragma unroll
    for (int j = 0; j < 4; ++j) {
        int k = k0 + ty + j * 8, n = n0 + tx;
        tile[ty + j * 8][tx] = (k < K && n < N) ? s[(size_t)k * N + n] : 0.f;
    }
    __syncthreads();
#pragma unroll
    for (int j = 0; j < 4; ++j) {
        int n = n0 + ty + j * 8, k = k0 + tx;
        if (n < Np && k < K) d[(size_t)n * K + k] = f2b(tile[tx][ty + j * 8]);
    }
}

// ---------------- bf16 MFMA GEMM: C[M,N] = A[M,K] @ Bt[N,K]^T ---------------
// BM=64, BN=128, BK=32; 256 threads = 4 waves, wave owns 64x32 (cols wv*32).
// EPI: 0 = plain store, 1 = +bias[n]+pos[(r%196)*N+n], 3 = += C (residual).
template <int EPI>
__global__ __launch_bounds__(256) void mfma_gemm(
    const u16* __restrict__ A, const u16* __restrict__ Bt,
    float* __restrict__ C, int ldc, int N, int K,
    const float* __restrict__ bias, const float* __restrict__ pos) {
    __shared__ __align__(16) u16 As[64][40];    // +8 pad: conflict-free b128 reads
    __shared__ __align__(16) u16 Bs[128][40];
    const int t = threadIdx.x;
    const int wv = t >> 6, lane = t & 63;
    const int row0 = blockIdx.y * 64, col0 = blockIdx.x * 128;
    const int r15 = lane & 15, half = lane >> 4;
    const int mA = t >> 2, kgA = (t & 3) * 8;

    f32x4 acc[4][2];
#pragma unroll
    for (int i = 0; i < 4; ++i)
#pragma unroll
        for (int j = 0; j < 2; ++j) acc[i][j] = (f32x4){0.f, 0.f, 0.f, 0.f};

    for (int k0 = 0; k0 < K; k0 += 32) {
        uint4 va  = *(const uint4*)(A  + (size_t)(row0 + mA) * K + k0 + kgA);
        uint4 vb0 = *(const uint4*)(Bt + (size_t)(col0 + mA) * K + k0 + kgA);
        uint4 vb1 = *(const uint4*)(Bt + (size_t)(col0 + 64 + mA) * K + k0 + kgA);
        __syncthreads();
        *(uint4*)&As[mA][kgA] = va;
        *(uint4*)&Bs[mA][kgA] = vb0;
        *(uint4*)&Bs[64 + mA][kgA] = vb1;
        __syncthreads();
        bf16x8 av[4], bv[2];
#pragma unroll
        for (int i = 0; i < 4; ++i) av[i] = *(const bf16x8*)&As[i * 16 + r15][half * 8];
#pragma unroll
        for (int j = 0; j < 2; ++j) bv[j] = *(const bf16x8*)&Bs[wv * 32 + j * 16 + r15][half * 8];
#pragma unroll
        for (int i = 0; i < 4; ++i)
#pragma unroll
            for (int j = 0; j < 2; ++j)
                acc[i][j] = __builtin_amdgcn_mfma_f32_16x16x32_bf16(av[i], bv[j], acc[i][j], 0, 0, 0);
    }

#pragma unroll
    for (int i = 0; i < 4; ++i) {
#pragma unroll
        for (int j = 0; j < 2; ++j) {
            int c = col0 + wv * 32 + j * 16 + r15;
            if (c < N) {
#pragma unroll
                for (int reg = 0; reg < 4; ++reg) {
                    int r = row0 + i * 16 + half * 4 + reg;
                    size_t idx = (size_t)r * ldc + c;
                    float v = acc[i][j][reg];
                    if (EPI == 1) v += bias[c] + pos[(size_t)(r % L_TOK) * N + c];
                    if (EPI == 3) v += C[idx];
                    C[idx] = v;
                }
            }
        }
    }
}

// ---------------- causal depthwise conv1d (d_conv=4) + SiLU -----------------
__global__ void conv_silu_kernel(const float* __restrict__ xz,
                                 const float* __restrict__ w,   // [768,4]
                                 const float* __restrict__ bb,  // [768]
                                 float* __restrict__ out, u16* __restrict__ outb) {
    int idx = blockIdx.x * 256 + threadIdx.x;  // ROWS*768
    int di = idx % 768;
    int row = idx / 768;
    int l = row % L_TOK;
    int rowbase = row - l;
    float s = bb[di];
#pragma unroll
    for (int j = 0; j < 4; ++j) {
        int ll = l - 3 + j;
        if (ll >= 0) s = fmaf(w[di * 4 + j], xz[(size_t)(rowbase + ll) * 1536 + di], s);
    }
    float v = s * sigmoidf_(s);
    out[(size_t)row * 768 + di] = v;
    outb[(size_t)row * 768 + di] = f2b(v);
}

// ---------------- LayerNorm (one wave per row, 384 elems) -------------------
template <int BF>
__global__ void ln_kernel(const float* __restrict__ in, const float* __restrict__ w,
                          const float* __restrict__ b, void* __restrict__ outp) {
    int row = blockIdx.x;
    int t = threadIdx.x;  // 0..63
    float v[6];
    float s1 = 0.f, s2 = 0.f;
#pragma unroll
    for (int j = 0; j < 6; ++j) {
        float xv = in[(size_t)row * 384 + t + j * 64];
        v[j] = xv;
        s1 += xv;
        s2 += xv * xv;
    }
#pragma unroll
    for (int off = 32; off >= 1; off >>= 1) {
        s1 += __shfl_xor(s1, off);
        s2 += __shfl_xor(s2, off);
    }
    float mu = s1 * (1.f / 384.f);
    float var = s2 * (1.f / 384.f) - mu * mu;
    float rs = rsqrtf(var + 1e-5f);
#pragma unroll
    for (int j = 0; j < 6; ++j) {
        int e = t + j * 64;
        float o = (v[j] - mu) * rs * w[e] + b[e];
        if (BF) ((u16*)outp)[(size_t)row * 384 + e] = f2b(o);
        else    ((float*)outp)[(size_t)row * 384 + e] = o;
    }
}

// ---------------- fused dt-GEMM + softplus + selective scan + gating --------
// One thread per (b, di); 16 states in registers; fully unrolled.
__global__ __launch_bounds__(64) void scan_kernel(
    const float* __restrict__ u,     // xconv [ROWS,768] fp32
    const float* __restrict__ xz,    // z at [row,768+di]
    const float* __restrict__ proj,  // [ROWS,56]: dt_in 0..23, B 24..39, C 40..55
    const float* __restrict__ dt_w,  // [24,768] layer slice
    const float* __restrict__ dt_b,  // [768]
    const float* __restrict__ A_log, // [768,16]
    const float* __restrict__ Dskip, // [768]
    u16* __restrict__ ygb)           // [ROWS,768] bf16
{
    const int di = blockIdx.y * 64 + threadIdx.x;
    const int b  = blockIdx.x;
    float dtw[24];
#pragma unroll
    for (int r = 0; r < 24; ++r) dtw[r] = dt_w[r * 768 + di];
    const float dtb0 = dt_b[di];
    const float dsk  = Dskip[di];
    float a[16];
#pragma unroll
    for (int n = 0; n < 16; ++n) a[n] = -__expf(A_log[di * 16 + n]);
    float h[16];
#pragma unroll
    for (int n = 0; n < 16; ++n) h[n] = 0.f;

    int row = b * L_TOK;
    for (int l = 0; l < L_TOK; ++l, ++row) {
        const float4* pr = (const float4*)(proj + (size_t)row * 56);
        float4 p0 = pr[0], p1 = pr[1], p2 = pr[2], p3 = pr[3], p4 = pr[4], p5 = pr[5];
        float4 q0 = pr[6], q1 = pr[7], q2 = pr[8], q3 = pr[9];     // B
        float4 c0 = pr[10], c1 = pr[11], c2 = pr[12], c3 = pr[13]; // C
        float uv = u[(size_t)row * 768 + di];
        float zv = xz[(size_t)row * 1536 + 768 + di];
        float dtv = dtb0;
        dtv += p0.x * dtw[0] + p0.y * dtw[1] + p0.z * dtw[2] + p0.w * dtw[3];
        dtv += p1.x * dtw[4] + p1.y * dtw[5] + p1.z * dtw[6] + p1.w * dtw[7];
        dtv += p2.x * dtw[8] + p2.y * dtw[9] + p2.z * dtw[10] + p2.w * dtw[11];
        dtv += p3.x * dtw[12] + p3.y * dtw[13] + p3.z * dtw[14] + p3.w * dtw[15];
        dtv += p4.x * dtw[16] + p4.y * dtw[17] + p4.z * dtw[18] + p4.w * dtw[19];
        dtv += p5.x * dtw[20] + p5.y * dtw[21] + p5.z * dtw[22] + p5.w * dtw[23];
        dtv = (dtv > 20.f) ? dtv : log1pf(__expf(dtv));   // softplus
        float du = dtv * uv;
        float Bv[16] = {q0.x, q0.y, q0.z, q0.w, q1.x, q1.y, q1.z, q1.w,
                        q2.x, q2.y, q2.z, q2.w, q3.x, q3.y, q3.z, q3.w};
        float Cv[16] = {c0.x, c0.y, c0.z, c0.w, c1.x, c1.y, c1.z, c1.w,
                        c2.x, c2.y, c2.z, c2.w, c3.x, c3.y, c3.z, c3.w};
        float y = 0.f;
#pragma unroll
        for (int n = 0; n < 16; ++n) {
            h[n] = __expf(dtv * a[n]) * h[n] + du * Bv[n];
            y = fmaf(h[n], Cv[n], y);
        }
        y = fmaf(uv, dsk, y);
        ygb[(size_t)row * 768 + di] = f2b(y * zv * sigmoidf_(zv));
    }
}

// ---------------- final: mean-pool + heads ----------------------------------
__global__ void pool_heads_kernel(const float* __restrict__ ln_out,  // [ROWS,384]
                                  const float* __restrict__ wdev, const float* __restrict__ bdev,
                                  const float* __restrict__ wdist, const float* __restrict__ bdist,
                                  float* __restrict__ out) {  // [16,11]
    __shared__ float pooled[384];
    int b = blockIdx.x;
    int m = threadIdx.x;  // 0..383
    float s = 0.f;
    for (int l = 0; l < L_TOK; ++l) s += ln_out[(size_t)(b * L_TOK + l) * 384 + m];
    pooled[m] = s * (1.f / (float)L_TOK);
    __syncthreads();
    if (m < 11) {
        float acc;
        const float* w;
        int nc, c;
        if (m < 7) { acc = bdev[m]; w = wdev; nc = 7; c = m; }
        else       { acc = bdist[m - 7]; w = wdist; nc = 4; c = m - 7; }
        for (int k = 0; k < 384; ++k) acc += pooled[k] * w[k * nc + c];
        out[b * 11 + m] = acc;
    }
}

extern "C" void kernel_launch(void* const* d_in, const int* in_sizes, int n_in,
                              void* d_out, int out_size, void* d_ws, size_t ws_size,
                              hipStream_t stream) {
    const float* x       = (const float*)d_in[0];
    const float* patch_w = (const float*)d_in[1];
    const float* patch_b = (const float*)d_in[2];
    const float* pos_emb = (const float*)d_in[3];
    const float* ln_w    = (const float*)d_in[4];
    const float* ln_b    = (const float*)d_in[5];
    const float* in_w    = (const float*)d_in[6];
    const float* conv_w  = (const float*)d_in[7];
    const float* conv_b  = (const float*)d_in[8];
    const float* xproj_w = (const float*)d_in[9];
    const float* dt_w    = (const float*)d_in[10];
    const float* dt_b    = (const float*)d_in[11];
    const float* A_log   = (const float*)d_in[12];
    const float* D_skip  = (const float*)d_in[13];
    const float* out_w   = (const float*)d_in[14];
    const float* fnorm_w = (const float*)d_in[15];
    const float* fnorm_b = (const float*)d_in[16];
    const float* hdev_w  = (const float*)d_in[17];
    const float* hdev_b  = (const float*)d_in[18];
    const float* hdist_w = (const float*)d_in[19];
    const float* hdist_b = (const float*)d_in[20];

    // -------- workspace carve-up (fp32 first, then bf16; all 16B aligned) ---
    float* fw = (float*)d_ws;
    float* h     = fw;                    // 3136*384
    float* xz    = h + 1204224;           // 3136*1536
    float* xconv = xz + 4816896;          // 3136*768 (also final-LN fp32 out)
    float* proj  = xconv + 2408448;       // 3136*56
    u16* uw = (u16*)(proj + 175616);
    u16* ygb      = uw;                   // 3136*768  (aliased: patches then yg)
    u16* patches  = ygb;
    u16* ub       = ygb + 2408448;        // 3136*384
    u16* xconvb   = ub + 1204224;         // 3136*768
    u16* Wt_patch = xconvb + 2408448;     // 384*768
    u16* Wt_in    = Wt_patch + 294912;    // 8*1536*384
    u16* Wt_xp    = Wt_in + 4718592;      // 8*128*768
    u16* Wt_out   = Wt_xp + 786432;       // 8*384*768

    // -------- weight prep: fp32 [K][N] -> bf16 [Np][K] ----------------------
    transpose_cvt<<<dim3(12, 24, 1), 256, 0, stream>>>(patch_w, Wt_patch, 768, 384, 384, 0, 0);
    transpose_cvt<<<dim3(48, 12, 8), 256, 0, stream>>>(in_w, Wt_in, 384, 1536, 1536, 384 * 1536, 1536 * 384);
    transpose_cvt<<<dim3(4, 24, 8), 256, 0, stream>>>(xproj_w, Wt_xp, 768, 56, 128, 768 * 56, 128 * 768);
    transpose_cvt<<<dim3(12, 24, 8), 256, 0, stream>>>(out_w, Wt_out, 768, 384, 384, 768 * 384, 384 * 768);

    patchify_kernel<<<ROWS, 256, 0, stream>>>(x, patches);
    // h = patches @ patch_w + patch_b + pos_emb
    mfma_gemm<1><<<dim3(3, 49), 256, 0, stream>>>(patches, Wt_patch, h, 384, 384, 768, patch_b, pos_emb);

    for (int i = 0; i < 8; ++i) {
        ln_kernel<1><<<ROWS, 64, 0, stream>>>(h, ln_w + i * 384, ln_b + i * 384, ub);
        // xz = u @ in_proj_w[i]   [3136,1536]
        mfma_gemm<0><<<dim3(12, 49), 256, 0, stream>>>(ub, Wt_in + (size_t)i * 1536 * 384,
                                                       xz, 1536, 1536, 384, nullptr, nullptr);
        conv_silu_kernel<<<9408, 256, 0, stream>>>(xz, conv_w + i * 3072, conv_b + i * 768, xconv, xconvb);
        // proj = xconv @ xproj_w[i]   [3136,56]
        mfma_gemm<0><<<dim3(1, 49), 256, 0, stream>>>(xconvb, Wt_xp + (size_t)i * 128 * 768,
                                                      proj, 56, 56, 768, nullptr, nullptr);
        // fused: dt = softplus(proj@dt_w + dt_b); scan; gate
        scan_kernel<<<dim3(16, 12), 64, 0, stream>>>(xconv, xz, proj, dt_w + (size_t)i * 24 * 768,
                                                     dt_b + i * 768, A_log + (size_t)i * 768 * 16,
                                                     D_skip + i * 768, ygb);
        // h += yg @ out_proj_w[i]
        mfma_gemm<3><<<dim3(3, 49), 256, 0, stream>>>(ygb, Wt_out + (size_t)i * 384 * 768,
                                                      h, 384, 384, 768, nullptr, nullptr);
    }
    ln_kernel<0><<<ROWS, 64, 0, stream>>>(h, fnorm_w, fnorm_b, xconv);
    pool_heads_kernel<<<16, 384, 0, stream>>>(xconv, hdev_w, hdev_b, hdist_w, hdist_b, (float*)d_out);
}

// Round 3
// 1302.630 us; speedup vs baseline: 2.8708x; 1.4329x over previous
//
#include <hip/hip_runtime.h>
#include <math.h>

// Vision Mamba: bf16-MFMA GEMMs + register-only chunked parallel scan.
// B=16, L=196, ROWS=3136, D_MODEL=384, D_INNER=768, N_STATE=16, DT_RANK=24, DEPTH=8.

#define L_TOK 196
#define ROWS  3136

typedef unsigned short u16;
typedef __attribute__((ext_vector_type(8))) short bf16x8;
typedef __attribute__((ext_vector_type(4))) float f32x4;

__device__ __forceinline__ float sigmoidf_(float x) { return 1.f / (1.f + __expf(-x)); }
__device__ __forceinline__ u16 f2b(float f) {
    union { float f; unsigned u; } v; v.f = f;
    unsigned r = v.u + 0x7FFF + ((v.u >> 16) & 1);
    return (u16)(r >> 16);
}

// ---------------- patchify: x[B,3,224,224] -> patches[3136,768] bf16 --------
__global__ void patchify_kernel(const float* __restrict__ x, u16* __restrict__ p) {
    int row = blockIdx.x;            // b*196 + l
    int t   = threadIdx.x;           // 0..255
    int b = row / L_TOK, l = row % L_TOK;
    int py = l / 14, px = l % 14;
    int iy = t >> 4, ix = t & 15;
    int Y = py * 16 + iy, X = px * 16 + ix;
#pragma unroll
    for (int c = 0; c < 3; ++c) {
        float v = x[((size_t)(b * 3 + c) * 224 + Y) * 224 + X];
        p[(size_t)row * 768 + c * 256 + t] = f2b(v);
    }
}

// ---------------- transpose+convert: src fp32 [K][N] -> dst bf16 [Np][K] ----
__global__ __launch_bounds__(256) void transpose_cvt(
    const float* __restrict__ src, u16* __restrict__ dst,
    int K, int N, int Np, int src_stride, int dst_stride) {
    __shared__ float tile[32][33];
    int n0 = blockIdx.x * 32, k0 = blockIdx.y * 32;
    const float* s = src + (size_t)blockIdx.z * src_stride;
    u16* d = dst + (size_t)blockIdx.z * dst_stride;
    int tx = threadIdx.x & 31, ty = threadIdx.x >> 5;   // 32 x 8
#pragma unroll
    for (int j = 0; j < 4; ++j) {
        int k = k0 + ty + j * 8, n = n0 + tx;
        tile[ty + j * 8][tx] = (k < K && n < N) ? s[(size_t)k * N + n] : 0.f;
    }
    __syncthreads();
#pragma unroll
    for (int j = 0; j < 4; ++j) {
        int n = n0 + ty + j * 8, k = k0 + tx;
        if (n < Np && k < K) d[(size_t)n * K + k] = f2b(tile[tx][ty + j * 8]);
    }
}

// ---------------- bf16 MFMA GEMM: C[M,N] = A[M,K] @ Bt[N,K]^T ---------------
// BM=64, BN=128, BK=32; 256 threads = 4 waves, wave owns 64x32 (cols wv*32).
// EPI: 0 = plain store, 1 = +bias[n]+pos[(r%196)*N+n], 3 = += C (residual).
template <int EPI>
__global__ __launch_bounds__(256) void mfma_gemm(
    const u16* __restrict__ A, const u16* __restrict__ Bt,
    float* __restrict__ C, int ldc, int N, int K,
    const float* __restrict__ bias, const float* __restrict__ pos) {
    __shared__ __align__(16) u16 As[64][40];    // +8 pad: conflict-free b128 reads
    __shared__ __align__(16) u16 Bs[128][40];
    const int t = threadIdx.x;
    const int wv = t >> 6, lane = t & 63;
    const int row0 = blockIdx.y * 64, col0 = blockIdx.x * 128;
    const int r15 = lane & 15, half = lane >> 4;
    const int mA = t >> 2, kgA = (t & 3) * 8;

    f32x4 acc[4][2];
#pragma unroll
    for (int i = 0; i < 4; ++i)
#pragma unroll
        for (int j = 0; j < 2; ++j) acc[i][j] = (f32x4){0.f, 0.f, 0.f, 0.f};

    for (int k0 = 0; k0 < K; k0 += 32) {
        uint4 va  = *(const uint4*)(A  + (size_t)(row0 + mA) * K + k0 + kgA);
        uint4 vb0 = *(const uint4*)(Bt + (size_t)(col0 + mA) * K + k0 + kgA);
        uint4 vb1 = *(const uint4*)(Bt + (size_t)(col0 + 64 + mA) * K + k0 + kgA);
        __syncthreads();
        *(uint4*)&As[mA][kgA] = va;
        *(uint4*)&Bs[mA][kgA] = vb0;
        *(uint4*)&Bs[64 + mA][kgA] = vb1;
        __syncthreads();
        bf16x8 av[4], bv[2];
#pragma unroll
        for (int i = 0; i < 4; ++i) av[i] = *(const bf16x8*)&As[i * 16 + r15][half * 8];
#pragma unroll
        for (int j = 0; j < 2; ++j) bv[j] = *(const bf16x8*)&Bs[wv * 32 + j * 16 + r15][half * 8];
#pragma unroll
        for (int i = 0; i < 4; ++i)
#pragma unroll
            for (int j = 0; j < 2; ++j)
                acc[i][j] = __builtin_amdgcn_mfma_f32_16x16x32_bf16(av[i], bv[j], acc[i][j], 0, 0, 0);
    }

#pragma unroll
    for (int i = 0; i < 4; ++i) {
#pragma unroll
        for (int j = 0; j < 2; ++j) {
            int c = col0 + wv * 32 + j * 16 + r15;
            if (c < N) {
#pragma unroll
                for (int reg = 0; reg < 4; ++reg) {
                    int r = row0 + i * 16 + half * 4 + reg;
                    size_t idx = (size_t)r * ldc + c;
                    float v = acc[i][j][reg];
                    if (EPI == 1) v += bias[c] + pos[(size_t)(r % L_TOK) * N + c];
                    if (EPI == 3) v += C[idx];
                    C[idx] = v;
                }
            }
        }
    }
}

// ---------------- causal depthwise conv1d (d_conv=4) + SiLU -----------------
__global__ void conv_silu_kernel(const float* __restrict__ xz,
                                 const float* __restrict__ w,   // [768,4]
                                 const float* __restrict__ bb,  // [768]
                                 float* __restrict__ out, u16* __restrict__ outb) {
    int idx = blockIdx.x * 256 + threadIdx.x;  // ROWS*768
    int di = idx % 768;
    int row = idx / 768;
    int l = row % L_TOK;
    int rowbase = row - l;
    float s = bb[di];
#pragma unroll
    for (int j = 0; j < 4; ++j) {
        int ll = l - 3 + j;
        if (ll >= 0) s = fmaf(w[di * 4 + j], xz[(size_t)(rowbase + ll) * 1536 + di], s);
    }
    float v = s * sigmoidf_(s);
    out[(size_t)row * 768 + di] = v;
    outb[(size_t)row * 768 + di] = f2b(v);
}

// ---------------- LayerNorm (one wave per row, 384 elems) -------------------
template <int BF>
__global__ void ln_kernel(const float* __restrict__ in, const float* __restrict__ w,
                          const float* __restrict__ b, void* __restrict__ outp) {
    int row = blockIdx.x;
    int t = threadIdx.x;  // 0..63
    float v[6];
    float s1 = 0.f, s2 = 0.f;
#pragma unroll
    for (int j = 0; j < 6; ++j) {
        float xv = in[(size_t)row * 384 + t + j * 64];
        v[j] = xv;
        s1 += xv;
        s2 += xv * xv;
    }
#pragma unroll
    for (int off = 32; off >= 1; off >>= 1) {
        s1 += __shfl_xor(s1, off);
        s2 += __shfl_xor(s2, off);
    }
    float mu = s1 * (1.f / 384.f);
    float var = s2 * (1.f / 384.f) - mu * mu;
    float rs = rsqrtf(var + 1e-5f);
#pragma unroll
    for (int j = 0; j < 6; ++j) {
        int e = t + j * 64;
        float o = (v[j] - mu) * rs * w[e] + b[e];
        if (BF) ((u16*)outp)[(size_t)row * 384 + e] = f2b(o);
        else    ((float*)outp)[(size_t)row * 384 + e] = o;
    }
}

// ---- fused dt-GEMM + softplus + CHUNKED selective scan + gating ------------
// Thread = (b, di, chunk). 16 chunks over L=196 (len 13 for c<4, else 12).
// Phase 1: local scan h0=0 -> (P[n], S[n]); dt,u cached in regs.
// Phase 2: segmented exclusive scan of (P,S) across 16 chunk-lanes (shfl_up).
// Phase 3: replay from h_in, emit y*silu(z) as bf16.
__global__ __launch_bounds__(256) void scan_kernel(
    const float* __restrict__ u,     // xconv [ROWS,768] fp32
    const float* __restrict__ xz,    // z at [row,768+di]
    const float* __restrict__ proj,  // [ROWS,56]: dt_in 0..23, B 24..39, C 40..55
    const float* __restrict__ dt_w,  // [24,768] layer slice
    const float* __restrict__ dt_b,  // [768]
    const float* __restrict__ A_log, // [768,16]
    const float* __restrict__ Dskip, // [768]
    u16* __restrict__ ygb)           // [ROWS,768] bf16
{
    const int tid = threadIdx.x;
    const int c  = tid & 15;         // chunk id, contiguous 16-lane segments
    const int dl = tid >> 4;         // 0..15
    const int di = blockIdx.y * 16 + dl;
    const int b  = blockIdx.x;
    const int start = (c < 4) ? c * 13 : 52 + (c - 4) * 12;
    const int len   = (c < 4) ? 13 : 12;
    const int row0  = b * L_TOK + start;

    float dtw[24];
#pragma unroll
    for (int r = 0; r < 24; ++r) dtw[r] = dt_w[r * 768 + di];
    const float dtb0 = dt_b[di];
    const float dsk  = Dskip[di];
    float a[16];
#pragma unroll
    for (int n = 0; n < 16; ++n) a[n] = -__expf(A_log[di * 16 + n]);

    float P[16], S[16];
#pragma unroll
    for (int n = 0; n < 16; ++n) { P[n] = 1.f; S[n] = 0.f; }
    float dts[13], us[13];

    // ---- phase 1: local scan ----
#pragma unroll
    for (int t = 0; t < 13; ++t) {
        bool act = (t < len);
        int row = act ? (row0 + t) : row0;
        const float4* pr = (const float4*)(proj + (size_t)row * 56);
        float4 p0 = pr[0], p1 = pr[1], p2 = pr[2], p3 = pr[3], p4 = pr[4], p5 = pr[5];
        float4 q0 = pr[6], q1 = pr[7], q2 = pr[8], q3 = pr[9];  // B
        float uv = u[(size_t)row * 768 + di];
        float dtv = dtb0;
        dtv += p0.x * dtw[0] + p0.y * dtw[1] + p0.z * dtw[2] + p0.w * dtw[3];
        dtv += p1.x * dtw[4] + p1.y * dtw[5] + p1.z * dtw[6] + p1.w * dtw[7];
        dtv += p2.x * dtw[8] + p2.y * dtw[9] + p2.z * dtw[10] + p2.w * dtw[11];
        dtv += p3.x * dtw[12] + p3.y * dtw[13] + p3.z * dtw[14] + p3.w * dtw[15];
        dtv += p4.x * dtw[16] + p4.y * dtw[17] + p4.z * dtw[18] + p4.w * dtw[19];
        dtv += p5.x * dtw[20] + p5.y * dtw[21] + p5.z * dtw[22] + p5.w * dtw[23];
        dtv = (dtv > 20.f) ? dtv : log1pf(__expf(dtv));   // softplus
        dts[t] = dtv;
        us[t]  = uv;
        if (act) {
            float du = dtv * uv;
            float Bv[16] = {q0.x, q0.y, q0.z, q0.w, q1.x, q1.y, q1.z, q1.w,
                            q2.x, q2.y, q2.z, q2.w, q3.x, q3.y, q3.z, q3.w};
#pragma unroll
            for (int n = 0; n < 16; ++n) {
                float e = __expf(dtv * a[n]);
                P[n] *= e;
                S[n] = fmaf(e, S[n], du * Bv[n]);
            }
        }
    }

    // ---- phase 2: segmented scan of (P,S) over 16 chunk-lanes ----
#pragma unroll
    for (int d = 1; d < 16; d <<= 1) {
#pragma unroll
        for (int n = 0; n < 16; ++n) {
            float Pp = __shfl_up(P[n], d, 16);
            float Sp = __shfl_up(S[n], d, 16);
            if (c >= d) {
                S[n] = fmaf(P[n], Sp, S[n]);
                P[n] *= Pp;
            }
        }
    }
    float h[16];
#pragma unroll
    for (int n = 0; n < 16; ++n) {
        float hin = __shfl_up(S[n], 1, 16);
        h[n] = (c == 0) ? 0.f : hin;
    }

    // ---- phase 3: replay with true h_in ----
#pragma unroll
    for (int t = 0; t < 13; ++t) {
        bool act = (t < len);
        int row = act ? (row0 + t) : row0;
        const float4* pr = (const float4*)(proj + (size_t)row * 56);
        float4 q0 = pr[6], q1 = pr[7], q2 = pr[8], q3 = pr[9];     // B
        float4 c0 = pr[10], c1 = pr[11], c2 = pr[12], c3 = pr[13]; // C
        float zv = xz[(size_t)row * 1536 + 768 + di];
        float dtv = dts[t], uv = us[t];
        float du = dtv * uv;
        float Bv[16] = {q0.x, q0.y, q0.z, q0.w, q1.x, q1.y, q1.z, q1.w,
                        q2.x, q2.y, q2.z, q2.w, q3.x, q3.y, q3.z, q3.w};
        float Cv[16] = {c0.x, c0.y, c0.z, c0.w, c1.x, c1.y, c1.z, c1.w,
                        c2.x, c2.y, c2.z, c2.w, c3.x, c3.y, c3.z, c3.w};
        float y = 0.f;
        if (act) {
#pragma unroll
            for (int n = 0; n < 16; ++n) {
                float e = __expf(dtv * a[n]);
                h[n] = fmaf(e, h[n], du * Bv[n]);
                y = fmaf(h[n], Cv[n], y);
            }
            y = fmaf(uv, dsk, y);
            ygb[(size_t)row * 768 + di] = f2b(y * zv * sigmoidf_(zv));
        }
    }
}

// ---------------- final: mean-pool + heads ----------------------------------
__global__ void pool_heads_kernel(const float* __restrict__ ln_out,  // [ROWS,384]
                                  const float* __restrict__ wdev, const float* __restrict__ bdev,
                                  const float* __restrict__ wdist, const float* __restrict__ bdist,
                                  float* __restrict__ out) {  // [16,11]
    __shared__ float pooled[384];
    int b = blockIdx.x;
    int m = threadIdx.x;  // 0..383
    float s = 0.f;
    for (int l = 0; l < L_TOK; ++l) s += ln_out[(size_t)(b * L_TOK + l) * 384 + m];
    pooled[m] = s * (1.f / (float)L_TOK);
    __syncthreads();
    if (m < 11) {
        float acc;
        const float* w;
        int nc, c;
        if (m < 7) { acc = bdev[m]; w = wdev; nc = 7; c = m; }
        else       { acc = bdist[m - 7]; w = wdist; nc = 4; c = m - 7; }
        for (int k = 0; k < 384; ++k) acc += pooled[k] * w[k * nc + c];
        out[b * 11 + m] = acc;
    }
}

extern "C" void kernel_launch(void* const* d_in, const int* in_sizes, int n_in,
                              void* d_out, int out_size, void* d_ws, size_t ws_size,
                              hipStream_t stream) {
    const float* x       = (const float*)d_in[0];
    const float* patch_w = (const float*)d_in[1];
    const float* patch_b = (const float*)d_in[2];
    const float* pos_emb = (const float*)d_in[3];
    const float* ln_w    = (const float*)d_in[4];
    const float* ln_b    = (const float*)d_in[5];
    const float* in_w    = (const float*)d_in[6];
    const float* conv_w  = (const float*)d_in[7];
    const float* conv_b  = (const float*)d_in[8];
    const float* xproj_w = (const float*)d_in[9];
    const float* dt_w    = (const float*)d_in[10];
    const float* dt_b    = (const float*)d_in[11];
    const float* A_log   = (const float*)d_in[12];
    const float* D_skip  = (const float*)d_in[13];
    const float* out_w   = (const float*)d_in[14];
    const float* fnorm_w = (const float*)d_in[15];
    const float* fnorm_b = (const float*)d_in[16];
    const float* hdev_w  = (const float*)d_in[17];
    const float* hdev_b  = (const float*)d_in[18];
    const float* hdist_w = (const float*)d_in[19];
    const float* hdist_b = (const float*)d_in[20];

    // -------- workspace carve-up (fp32 first, then bf16; all 16B aligned) ---
    float* fw = (float*)d_ws;
    float* h     = fw;                    // 3136*384
    float* xz    = h + 1204224;           // 3136*1536
    float* xconv = xz + 4816896;          // 3136*768 (also final-LN fp32 out)
    float* proj  = xconv + 2408448;       // 3136*56
    u16* uw = (u16*)(proj + 175616);
    u16* ygb      = uw;                   // 3136*768  (aliased: patches then yg)
    u16* patches  = ygb;
    u16* ub       = ygb + 2408448;        // 3136*384
    u16* xconvb   = ub + 1204224;         // 3136*768
    u16* Wt_patch = xconvb + 2408448;     // 384*768
    u16* Wt_in    = Wt_patch + 294912;    // 8*1536*384
    u16* Wt_xp    = Wt_in + 4718592;      // 8*128*768
    u16* Wt_out   = Wt_xp + 786432;       // 8*384*768

    // -------- weight prep: fp32 [K][N] -> bf16 [Np][K] ----------------------
    transpose_cvt<<<dim3(12, 24, 1), 256, 0, stream>>>(patch_w, Wt_patch, 768, 384, 384, 0, 0);
    transpose_cvt<<<dim3(48, 12, 8), 256, 0, stream>>>(in_w, Wt_in, 384, 1536, 1536, 384 * 1536, 1536 * 384);
    transpose_cvt<<<dim3(4, 24, 8), 256, 0, stream>>>(xproj_w, Wt_xp, 768, 56, 128, 768 * 56, 128 * 768);
    transpose_cvt<<<dim3(12, 24, 8), 256, 0, stream>>>(out_w, Wt_out, 768, 384, 384, 768 * 384, 384 * 768);

    patchify_kernel<<<ROWS, 256, 0, stream>>>(x, patches);
    // h = patches @ patch_w + patch_b + pos_emb
    mfma_gemm<1><<<dim3(3, 49), 256, 0, stream>>>(patches, Wt_patch, h, 384, 384, 768, patch_b, pos_emb);

    for (int i = 0; i < 8; ++i) {
        ln_kernel<1><<<ROWS, 64, 0, stream>>>(h, ln_w + i * 384, ln_b + i * 384, ub);
        // xz = u @ in_proj_w[i]   [3136,1536]
        mfma_gemm<0><<<dim3(12, 49), 256, 0, stream>>>(ub, Wt_in + (size_t)i * 1536 * 384,
                                                       xz, 1536, 1536, 384, nullptr, nullptr);
        conv_silu_kernel<<<9408, 256, 0, stream>>>(xz, conv_w + i * 3072, conv_b + i * 768, xconv, xconvb);
        // proj = xconv @ xproj_w[i]   [3136,56]
        mfma_gemm<0><<<dim3(1, 49), 256, 0, stream>>>(xconvb, Wt_xp + (size_t)i * 128 * 768,
                                                      proj, 56, 56, 768, nullptr, nullptr);
        // fused: dt = softplus(proj@dt_w + dt_b); chunked scan; gate
        scan_kernel<<<dim3(16, 48), 256, 0, stream>>>(xconv, xz, proj, dt_w + (size_t)i * 24 * 768,
                                                      dt_b + i * 768, A_log + (size_t)i * 768 * 16,
                                                      D_skip + i * 768, ygb);
        // h += yg @ out_proj_w[i]
        mfma_gemm<3><<<dim3(3, 49), 256, 0, stream>>>(ygb, Wt_out + (size_t)i * 384 * 768,
                                                      h, 384, 384, 768, nullptr, nullptr);
    }
    ln_kernel<0><<<ROWS, 64, 0, stream>>>(h, fnorm_w, fnorm_b, xconv);
    pool_heads_kernel<<<16, 384, 0, stream>>>(xconv, hdev_w, hdev_b, hdist_w, hdist_b, (float*)d_out);
}